// Round 10
// baseline (215.522 us; speedup 1.0000x reference)
//
#include <hip/hip_runtime.h>
#include <stdint.h>

typedef int v4i __attribute__((ext_vector_type(4)));

// Problem constants
constexpr int C     = 256;           // channels (in == out)
constexpr int H     = 28, W = 28;
constexpr int HW    = H * W;         // 784
constexpr int NB    = 64;            // batch
constexpr int GP    = NB * HW;       // 50176 flattened pixels
constexpr int CNT   = GP;            // per-channel reduction count
constexpr int TOTAL = NB * C * HW;   // 12,845,056
constexpr int MT    = 112;           // pixels per block
constexpr int NBLK  = GP / MT;       // 448 conv tiles, exact
constexpr int LROWS = 176;           // staged rows: gp0-32 .. gp0+143
constexpr int ZROW  = LROWS * 16;    // zero-row base (v4i index)

// ---------------------------------------------------------------------------
// R15 = R14 resubmitted verbatim (R14 bench was an infra failure, not a
// kernel verdict). Tail overhaul vs R13:
// (a) pack_x & signpack: 4 consecutive pixels/thread via float4/short4 —
//     4x fewer load instrs, one 64B contiguous store per thread.
// (b) finalize restored as its own 1-block kernel (fp64 once) — the fused
//     form re-ran 256 fp64 div+sqrt in EVERY signpack/bn_clip block.
// (c) conv kernels byte-identical to R13 (canary: 46.0 us each).
// Frag order (A and B identical) for mfma_i32_16x16x64_i8: lane l holds
// ch = g*16 + (l&15), k = (l>>4)*16+e. wbf[((tp*4+kb)*16+g)*64+l].
// +1 -> 0x01, -1 -> 0xFF, zero-pad = 0x00.
// ---------------------------------------------------------------------------

#define SB(f) ((f) < 0.f ? 0xFF : 0x01)

// one channel e: float4 = 4 consecutive pixels; accumulate into per-pixel words
#define XPE(e, pw0, pw1, pw2, pw3, sh) { \
    const float4 v = *(const float4*)(base + (size_t)(e) * HW); \
    pw0 |= SB(v.x) << (sh); pw1 |= SB(v.y) << (sh); \
    pw2 |= SB(v.z) << (sh); pw3 |= SB(v.w) << (sh); }

__global__ void pack_all_kernel(const float* __restrict__ pw1, const float* __restrict__ pw2,
                                const float* __restrict__ x,
                                v4i* __restrict__ wbf1, v4i* __restrict__ wbf2,
                                v4i* __restrict__ xb, double* __restrict__ stats) {
    __shared__ signed char sgn[36864];     // 16 co x 2304 (ci,tap) sign bytes
    const int t = threadIdx.x;
    const int bid = blockIdx.x;
    if (bid < 32) {                        // w-part: (tensor, g) LDS transpose
        const int g = bid & 15;
        const float* w = (bid >> 4) ? pw2 : pw1;
        v4i* dst       = (bid >> 4) ? wbf2 : wbf1;
        const float4* wg = (const float4*)(w + (size_t)g * 16 * 2304);
        int* sg4 = (int*)sgn;
        for (int pass = 0; pass < 36; ++pass) {        // 9216 float4 / 256
            const int m4 = pass * 256 + t;
            float4 v = wg[m4];
            int pk = SB(v.x) | (SB(v.y) << 8) | (SB(v.z) << 16) | (SB(v.w) << 24);
            sg4[m4] = pk;
        }
        __syncthreads();
        const int l = t & 63, kb = t >> 6;
        const int colb = (l & 15) * 2304;              // co_local * 2304
        const int cib  = kb * 64 + (l >> 4) * 16;      // ci0
        for (int tp = 0; tp < 9; ++tp) {
            int b0 = 0, b1 = 0, b2 = 0, b3 = 0;
#pragma unroll
            for (int e = 0; e < 16; ++e) {
                int b = (int)(unsigned char)sgn[colb + (cib + e) * 9 + tp];
                int sh = (e & 3) * 8;
                if (e < 4) b0 |= b << sh; else if (e < 8) b1 |= b << sh;
                else if (e < 12) b2 |= b << sh; else b3 |= b << sh;
            }
            v4i o; o.x = b0; o.y = b1; o.z = b2; o.w = b3;
            dst[((tp * 4 + kb) * 16 + g) * 64 + l] = o;
        }
    } else {
        // x-part: 784 blocks; thread = (ch-chunk, 4 consecutive pixels)
        const int local = bid - 32;            // 0..783
        const int ch = local / 49;             // 16 chunks
        const int i4 = (local % 49) * 256 + t; // 0..12543
        if (ch == 0 && i4 < 1024) stats[i4] = 0.0;  // zero all 4 stat arrays
        const int gp = i4 * 4;
        const int n = gp / HW, p = gp % HW;    // p..p+3 within one image (784%4==0)
        const float* base = x + (size_t)n * C * HW + (size_t)(ch * 16) * HW + p;
        int a0=0,a1=0,a2=0,a3=0;   // pixel0 words
        int b0=0,b1=0,b2=0,b3=0;   // pixel1
        int c0=0,c1=0,c2=0,c3=0;   // pixel2
        int d0=0,d1=0,d2=0,d3=0;   // pixel3
        XPE( 0,a0,b0,c0,d0, 0) XPE( 1,a0,b0,c0,d0, 8) XPE( 2,a0,b0,c0,d0,16) XPE( 3,a0,b0,c0,d0,24)
        XPE( 4,a1,b1,c1,d1, 0) XPE( 5,a1,b1,c1,d1, 8) XPE( 6,a1,b1,c1,d1,16) XPE( 7,a1,b1,c1,d1,24)
        XPE( 8,a2,b2,c2,d2, 0) XPE( 9,a2,b2,c2,d2, 8) XPE(10,a2,b2,c2,d2,16) XPE(11,a2,b2,c2,d2,24)
        XPE(12,a3,b3,c3,d3, 0) XPE(13,a3,b3,c3,d3, 8) XPE(14,a3,b3,c3,d3,16) XPE(15,a3,b3,c3,d3,24)
        v4i* dst = xb + (size_t)ch * GP + gp;
        v4i o0; o0.x=a0; o0.y=a1; o0.z=a2; o0.w=a3; dst[0] = o0;
        v4i o1; o1.x=b0; o1.y=b1; o1.z=b2; o1.w=b3; dst[1] = o1;
        v4i o2; o2.x=c0; o2.y=c1; o2.z=c2; o2.w=c3; dst[2] = o2;
        v4i o3; o3.x=d0; o3.y=d1; o3.z=d2; o3.w=d3; dst[3] = o3;
    }
}

// ---------------------------------------------------------------------------
// BN stats -> per-channel scale/shift (fp64 once, 1 block)
// ---------------------------------------------------------------------------
__global__ void finalize_kernel(const double* __restrict__ sum,
                                const double* __restrict__ sumsq,
                                const float* __restrict__ gamma,
                                const float* __restrict__ beta,
                                float* __restrict__ scale,
                                float* __restrict__ shift) {
    int c = threadIdx.x;  // 256 threads
    double mean = sum[c] / (double)CNT;
    double var  = sumsq[c] / (double)CNT - mean * mean;
    double inv  = 1.0 / sqrt(var + 1e-5);
    scale[c] = (float)inv * gamma[c];
    shift[c] = beta[c] - (float)(mean * inv) * gamma[c];
}

// ---------------------------------------------------------------------------
// BN1 + binarize -> i8 plane-major (coefs precomputed; 4 pixels/thread).
// sign(clip(z)) == sign(z); binarize(0)=+1.
// ---------------------------------------------------------------------------
typedef short short4v __attribute__((ext_vector_type(4)));

#define SPE(e, pw0, pw1, pw2, pw3, sh) { \
    const short4v v = *(const short4v*)(base + (size_t)(e) * HW); \
    const float sc = s_scale[chb + (e)], sf = s_shift[chb + (e)]; \
    pw0 |= SB((float)v.x * sc + sf) << (sh); pw1 |= SB((float)v.y * sc + sf) << (sh); \
    pw2 |= SB((float)v.z * sc + sf) << (sh); pw3 |= SB((float)v.w * sc + sf) << (sh); }

__global__ void bn_signpack_kernel(const short* __restrict__ y,
                                   const float* __restrict__ scale,
                                   const float* __restrict__ shift,
                                   v4i* __restrict__ xb) {
    __shared__ float s_scale[C], s_shift[C];
    const int t = threadIdx.x;
    s_scale[t] = scale[t]; s_shift[t] = shift[t];
    __syncthreads();
    const int local = blockIdx.x;          // 784 blocks
    const int ch = local / 49;
    const int i4 = (local % 49) * 256 + t;
    const int gp = i4 * 4;
    const int n = gp / HW, p = gp % HW;
    const short* base = y + (size_t)n * C * HW + (size_t)(ch * 16) * HW + p;
    const int chb = ch * 16;
    int a0=0,a1=0,a2=0,a3=0;
    int b0=0,b1=0,b2=0,b3=0;
    int c0=0,c1=0,c2=0,c3=0;
    int d0=0,d1=0,d2=0,d3=0;
    SPE( 0,a0,b0,c0,d0, 0) SPE( 1,a0,b0,c0,d0, 8) SPE( 2,a0,b0,c0,d0,16) SPE( 3,a0,b0,c0,d0,24)
    SPE( 4,a1,b1,c1,d1, 0) SPE( 5,a1,b1,c1,d1, 8) SPE( 6,a1,b1,c1,d1,16) SPE( 7,a1,b1,c1,d1,24)
    SPE( 8,a2,b2,c2,d2, 0) SPE( 9,a2,b2,c2,d2, 8) SPE(10,a2,b2,c2,d2,16) SPE(11,a2,b2,c2,d2,24)
    SPE(12,a3,b3,c3,d3, 0) SPE(13,a3,b3,c3,d3, 8) SPE(14,a3,b3,c3,d3,16) SPE(15,a3,b3,c3,d3,24)
    v4i* dst = xb + (size_t)ch * GP + gp;
    v4i o0; o0.x=a0; o0.y=a1; o0.z=a2; o0.w=a3; dst[0] = o0;
    v4i o1; o1.x=b0; o1.y=b1; o1.z=b2; o1.w=b3; dst[1] = o1;
    v4i o2; o2.x=c0; o2.y=c1; o2.z=c2; o2.w=c3; dst[2] = o2;
    v4i o3; o3.x=d0; o3.y=d1; o3.z=d2; o3.w=d3; dst[3] = o3;
}

// ---------------------------------------------------------------------------
// bconv: UNCHANGED from R13 (banked: 46 us, MfmaUtil 23.5). MT=112, ping-pong
// double-buffer, zero-row border select, vectorized epilogue + stats.
// ---------------------------------------------------------------------------

#define ACCD(m) v4i c##m##_0={0,0,0,0}, c##m##_1={0,0,0,0}, \
                    c##m##_2={0,0,0,0}, c##m##_3={0,0,0,0};
#define ACC_DECL ACCD(0) ACCD(1) ACCD(2) ACCD(3) ACCD(4) ACCD(5) ACCD(6)

#define MFMA(a,b,c) c = __builtin_amdgcn_mfma_i32_16x16x64_i8(a, b, c, 0, 0, 0);

#define B_LOADQ(P, idx) { const v4i* bp = wbf + (idx); \
    P##0 = bp[0]; P##1 = bp[64]; P##2 = bp[128]; P##3 = bp[192]; }

#define ARD(P, m, cb) P##m = xl[R##m + ((cb) ^ S##m)];
#define ARDALL(P, cb) ARD(P,0,cb) ARD(P,1,cb) ARD(P,2,cb) ARD(P,3,cb) \
                      ARD(P,4,cb) ARD(P,5,cb) ARD(P,6,cb)

#define MFMAG(A,B,g) MFMA(A##0,B##g,c0_##g) MFMA(A##1,B##g,c1_##g) MFMA(A##2,B##g,c2_##g) \
                     MFMA(A##3,B##g,c3_##g) MFMA(A##4,B##g,c4_##g) MFMA(A##5,B##g,c5_##g) \
                     MFMA(A##6,B##g,c6_##g)
#define MFMA_C(A,B) __builtin_amdgcn_s_setprio(1); \
    MFMAG(A,B,0) MFMAG(A,B,1) MFMAG(A,B,2) MFMAG(A,B,3) \
    __builtin_amdgcn_s_setprio(0);

#define TV1(m) { const bool mk = ((unsigned)(cm##m + dc) < 28u) && \
                                 ((unsigned)(rm##m + dr) < 28u); \
    R##m = mk ? (lrb + 16 * (m)) * 16 : ZROW; S##m = mk ? sm : 0; }
#define TAPVARS(TPX) { const int dr = (TPX)/3 - 1, dc = (TPX)%3 - 1; \
    const int lrb = 32 + llo + dr * W + dc; const int sm = lrb & 15; \
    TV1(0) TV1(1) TV1(2) TV1(3) TV1(4) TV1(5) TV1(6) }

#define PMV(m) const int gx##m = gp0 + (m)*16 + llo; \
    const int pmv##m = gx##m % HW; \
    const int rm##m = pmv##m / W, cm##m = pmv##m % W;

#define EPIV(m,g) { \
    const int gpv = gp0 + (m)*16 + lhi*4; \
    const int nn = gpv / HW; const int pp = gpv - nn*HW; \
    const size_t base = (size_t)nn*(C*HW) + (size_t)(wn*64+(g)*16+llo)*HW + pp; \
    const v4i cc = c##m##_##g; \
    if constexpr (HAS_RES) { \
        const float4 r = *(const float4*)(residual + base); \
        float4 o; o.x = (float)cc.x + r.x; o.y = (float)cc.y + r.y; \
        o.z = (float)cc.z + r.z; o.w = (float)cc.w + r.w; \
        *(float4*)((float*)yout + base) = o; \
        sy##g += o.x + o.y + o.z + o.w; \
        sq##g += o.x*o.x + o.y*o.y + o.z*o.z + o.w*o.w; \
    } else { \
        int2 o; o.x = (cc.x & 0xFFFF) | (cc.y << 16); \
        o.y = (cc.z & 0xFFFF) | (cc.w << 16); \
        *(int2*)((short*)yout + base) = o; \
        const float fx = (float)cc.x, fy = (float)cc.y, fz = (float)cc.z, fw = (float)cc.w; \
        sy##g += fx + fy + fz + fw; \
        sq##g += fx*fx + fy*fy + fz*fz + fw*fw; \
    } }
#define EPIM(m) EPIV(m,0) EPIV(m,1) EPIV(m,2) EPIV(m,3)

#define REDN(g) { float s1 = sy##g, s2 = sq##g; \
    s1 += __shfl_down(s1, 32); s1 += __shfl_down(s1, 16); \
    s2 += __shfl_down(s2, 32); s2 += __shfl_down(s2, 16); \
    if (l < 16) { const int co = wn*64 + (g)*16 + l; \
        atomicAdd(&sum[co], (double)s1); atomicAdd(&sumsq[co], (double)s2); } }

template<bool HAS_RES, typename OUT_T>
__launch_bounds__(256, 2)
__global__ void bconv_mfma(const v4i* __restrict__ xb,
                           const v4i* __restrict__ wbf,
                           const float* __restrict__ residual,
                           OUT_T* __restrict__ yout,
                           double* __restrict__ sum, double* __restrict__ sumsq) {
    __shared__ v4i xl[LROWS * 16 + 16];     // 176 data rows + zero row (45.3 KB)
    const int t   = threadIdx.x;
    const int gp0 = blockIdx.x * MT;

    // stage 176 rows x 16 chunks, coalesced reads, swizzled LDS writes
    for (int pass = 0; pass < 11; ++pass) {
        const int i = pass * 256 + t;
        const int c = i / LROWS;            // plane 0..15
        const int r = i - c * LROWS;        // local row 0..175
        int gsrc = min(max(gp0 - 32 + r, 0), GP - 1);
        xl[r * 16 + (c ^ (r & 15))] = xb[(size_t)c * GP + gsrc];
    }
    if (t < 16) { v4i z = {0,0,0,0}; xl[ZROW + t] = z; }   // zero row
    __syncthreads();

    const int l = t & 63, wn = t >> 6;
    const int llo = l & 15, lhi = l >> 4;

    PMV(0) PMV(1) PMV(2) PMV(3) PMV(4) PMV(5) PMV(6)

    ACC_DECL
    const int bw = wn * 256 + l;

    int R0,R1,R2,R3,R4,R5,R6, S0,S1,S2,S3,S4,S5,S6;
    TAPVARS(0)
    v4i bP0,bP1,bP2,bP3, bQ0,bQ1,bQ2,bQ3;
    v4i aP0,aP1,aP2,aP3,aP4,aP5,aP6, aQ0,aQ1,aQ2,aQ3,aQ4,aQ5,aQ6;
    B_LOADQ(bP, bw)                 // (tap0, kb0)
    ARDALL(aP, lhi)

#pragma unroll 1
    for (int tp = 0; tp < 9; ++tp) {
        const int tb = bw + tp * 4096;
        // kb0: prefetch (tp,1); compute (tp,0)
        B_LOADQ(bQ, tb + 1024)
        ARDALL(aQ, 4 + lhi)
        MFMA_C(aP, bP)
        // kb1: prefetch (tp,2); compute (tp,1)
        B_LOADQ(bP, tb + 2048)
        ARDALL(aP, 8 + lhi)
        MFMA_C(aQ, bQ)
        // kb2: prefetch (tp,3); compute (tp,2)
        B_LOADQ(bQ, tb + 3072)
        ARDALL(aQ, 12 + lhi)
        MFMA_C(aP, bP)
        // kb3: next-tap vars; prefetch (tp+1,0); compute (tp,3)
        const int tpn = (tp < 8) ? tp + 1 : 8;
        TAPVARS(tpn)
        B_LOADQ(bP, bw + tpn * 4096)
        ARDALL(aP, lhi)
        MFMA_C(aQ, bQ)
    }

    // ---- epilogue: vectorized store + per-channel stats ----
    float sy0 = 0, sy1 = 0, sy2 = 0, sy3 = 0;
    float sq0 = 0, sq1 = 0, sq2 = 0, sq3 = 0;
    EPIM(0) EPIM(1) EPIM(2) EPIM(3) EPIM(4) EPIM(5) EPIM(6)
    REDN(0) REDN(1) REDN(2) REDN(3)
}

// ---------------------------------------------------------------------------
// Final: out = clip(z*scale[c] + shift[c], -1, 1), float4 (coefs precomputed)
// ---------------------------------------------------------------------------
__global__ void bn_clip_kernel(const float4* __restrict__ z,
                               const float* __restrict__ scale,
                               const float* __restrict__ shift,
                               float4* __restrict__ out) {
    __shared__ float s_scale[C], s_shift[C];
    const int t = threadIdx.x;
    s_scale[t] = scale[t]; s_shift[t] = shift[t];
    __syncthreads();
    for (int i = blockIdx.x * blockDim.x + t; i < TOTAL / 4;
         i += gridDim.x * blockDim.x) {
        int c = (i / (HW / 4)) & (C - 1);
        float s = s_scale[c], b = s_shift[c];
        float4 v = z[i];
        v.x = fminf(1.f, fmaxf(-1.f, v.x * s + b));
        v.y = fminf(1.f, fmaxf(-1.f, v.y * s + b));
        v.z = fminf(1.f, fmaxf(-1.f, v.z * s + b));
        v.w = fminf(1.f, fmaxf(-1.f, v.w * s + b));
        out[i] = v;
    }
}

// ---------------------------------------------------------------------------
extern "C" void kernel_launch(void* const* d_in, const int* in_sizes, int n_in,
                              void* d_out, int out_size, void* d_ws, size_t ws_size,
                              hipStream_t stream) {
    const float* x  = (const float*)d_in[0];
    const float* w1 = (const float*)d_in[1];
    const float* w2 = (const float*)d_in[2];
    const float* g1 = (const float*)d_in[3];
    const float* b1 = (const float*)d_in[4];
    const float* g2 = (const float*)d_in[5];
    const float* b2 = (const float*)d_in[6];
    float* out = (float*)d_out;

    char* ws = (char*)d_ws;
    size_t off = 0;
    float* z2 = (float*)(ws + off);   off += (size_t)TOTAL * 4;        // 51.4 MB
    v4i* xb1  = (v4i*)(ws + off);     off += (size_t)GP * 16 * 16;     // 12.85 MB
    v4i* xb2  = (v4i*)(ws + off);     off += (size_t)GP * 16 * 16;     // 12.85 MB
    v4i* wbf1 = (v4i*)(ws + off);     off += (size_t)36864 * 16;       // 590 KB
    v4i* wbf2 = (v4i*)(ws + off);     off += (size_t)36864 * 16;
    double* stats = (double*)(ws + off); off += 4 * 256 * 8;
    double* sum1 = stats, *sumsq1 = stats + 256, *sum2 = stats + 512, *sumsq2 = stats + 768;
    float* coefs = (float*)(ws + off);   off += 4 * 256 * 4;
    float* scale1 = coefs, *shift1 = coefs + 256, *scale2 = coefs + 512, *shift2 = coefs + 768;

    // y1 (i16) lives in d_out as scratch; fully rewritten by bn_clip at the end
    short* y1 = (short*)d_out;

    // pre-pass: weight packs (LDS-transpose) + x pack (4px/thread) + stats zero
    pack_all_kernel<<<32 + 784, 256, 0, stream>>>(w1, w2, x, wbf1, wbf2, xb1, stats);

    // conv1: y1 (i16) -> d_out scratch, fused BN1 stats
    bconv_mfma<false, short><<<NBLK, 256, 0, stream>>>(xb1, wbf1, nullptr, y1, sum1, sumsq1);
    // BN1 coefs (fp64 once)
    finalize_kernel<<<1, 256, 0, stream>>>(sum1, sumsq1, g1, b1, scale1, shift1);
    // BN1 + hardtanh + binarize -> i8 planes (4px/thread)
    bn_signpack_kernel<<<784, 256, 0, stream>>>(y1, scale1, shift1, xb2);
    // conv2 + residual, fused BN2 stats, z2 -> ws
    bconv_mfma<true, float><<<NBLK, 256, 0, stream>>>(xb2, wbf2, x, z2, sum2, sumsq2);
    // BN2 coefs (fp64 once)
    finalize_kernel<<<1, 256, 0, stream>>>(sum2, sumsq2, g2, b2, scale2, shift2);
    // BN2 + hardtanh -> out
    bn_clip_kernel<<<4096, 256, 0, stream>>>((const float4*)z2, scale2, shift2, (float4*)out);
}